// Round 18
// baseline (266.623 us; speedup 1.0000x reference)
//
#include <hip/hip_runtime.h>

#define NN 100000
#define NE 3200000
#define DIN 128
#define HD 64
#define DEMB 32
#define NG 256
#define NBUCK ((NN + 255) / 256)        // 391 coarse buckets of 256 dst-nodes
#define NPB 512                         // partition blocks
#define CHUNK ((NE + NPB - 1) / NPB)    // 6250 edges per partition block
#define NM (NBUCK * NPB)                // 200192 histogram-matrix entries
#define NMB ((NM + 1023) / 1024)        // 196 scan blocks
#define BCAP 10240                      // phaseB LDS bucket cap (mean 8192, +22 sigma)

typedef unsigned short u16;
typedef unsigned int u32;
typedef __attribute__((ext_vector_type(8))) short bf16x8;
typedef __attribute__((ext_vector_type(4))) float f32x4;
typedef __attribute__((ext_vector_type(2))) float f32x2;

__device__ __forceinline__ float bflo(u32 u) { return __uint_as_float(u << 16); }
__device__ __forceinline__ float bfhi(u32 u) { return __uint_as_float(u & 0xffff0000u); }
__device__ __forceinline__ u16 f2bf(float f) {          // round-to-nearest-even
    u32 u = __float_as_uint(f);
    return (u16)((u + 0x7fffu + ((u >> 16) & 1u)) >> 16);
}
__device__ __forceinline__ f32x2 unpk(u32 u) {          // {lo, hi} bf16 -> f32 pair
    f32x2 r; r.x = bflo(u); r.y = bfhi(u); return r;
}

// ---------------- pass A: per-block coarse histogram (no global atomics) -----
__global__ __launch_bounds__(256) void k_blkhist(const int* __restrict__ dst,
                                                 int* __restrict__ HM, int E) {
    __shared__ int h[NBUCK];
    int blk = blockIdx.x, t = threadIdx.x;
    for (int i = t; i < NBUCK; i += 256) h[i] = 0;
    __syncthreads();
    int beg = blk * CHUNK, end = min(E, beg + CHUNK);
    for (int j = beg + t; j < end; j += 256) atomicAdd(&h[dst[j] >> 8], 1);
    __syncthreads();
    for (int i = t; i < NBUCK; i += 256) HM[i * NPB + blk] = h[i];  // bucket-major
}

// ---------------- scan pass 1: in-place per-1024-block exclusive scan --------
__global__ __launch_bounds__(1024) void k_scanA(int* __restrict__ HM,
                                                int* __restrict__ bsum, int n) {
    __shared__ int s[1024];
    int t = threadIdx.x;
    int idx = blockIdx.x * 1024 + t;
    int v = (idx < n) ? HM[idx] : 0;
    s[t] = v;
    __syncthreads();
    for (int off = 1; off < 1024; off <<= 1) {
        int add = (t >= off) ? s[t - off] : 0;
        __syncthreads();
        s[t] += add;
        __syncthreads();
    }
    if (idx < n) HM[idx] = s[t] - v;            // exclusive within block
    if (t == 1023) bsum[blockIdx.x] = s[t];     // block total
}

// ---------------- pass C: place edges; local bsum-scan replaces scan2/scanC --
// part[pos] = src | (dst&255)<<17 ; block 0 emits crow[] (absolute bucket starts)
__global__ __launch_bounds__(256) void k_place(const int* __restrict__ src,
                                               const int* __restrict__ dst,
                                               const int* __restrict__ HM,
                                               const int* __restrict__ bsum,
                                               int* __restrict__ part,
                                               int* __restrict__ crow, int E) {
    __shared__ int cur[NBUCK];
    __shared__ int sb[256];
    __shared__ int sbe[256];    // exclusive scan of bsum
    int blk = blockIdx.x, t = threadIdx.x;
    int v = (t < NMB) ? bsum[t] : 0;
    sb[t] = v;
    __syncthreads();
    for (int off = 1; off < 256; off <<= 1) {
        int add = (t >= off) ? sb[t - off] : 0;
        __syncthreads();
        sb[t] += add;
        __syncthreads();
    }
    sbe[t] = sb[t] - v;
    __syncthreads();
    for (int i = t; i < NBUCK; i += 256) {
        int idx = i * NPB + blk;
        int absv = HM[idx] + sbe[idx >> 10];
        cur[i] = absv;
        if (blk == 0) crow[i] = absv;   // blk 0 cursor = absolute bucket start
    }
    if (blk == 0 && t == 0) crow[NBUCK] = E;
    __syncthreads();
    int beg = blk * CHUNK, end = min(E, beg + CHUNK);
    for (int j = beg + t; j < end; j += 256) {
        int d = dst[j], s = src[j];
        int pos = atomicAdd(&cur[d >> 8], 1);   // LDS atomic — no global contention
        part[pos] = s | ((d & 255) << 17);
    }
}

// ---------------- phase B: per-bucket fine sort + degree + rowptr + dinv -----
// bucket staged in LDS (one global read instead of two); crow gives ranges.
__global__ __launch_bounds__(256) void k_phaseB(const int* __restrict__ part,
                                                const int* __restrict__ crow,
                                                int* __restrict__ rowptr,
                                                int* __restrict__ ssrc,
                                                float* __restrict__ dinv, int E) {
    __shared__ int cnt[256];
    __shared__ int sc[256];
    __shared__ int ebuf[BCAP];
    int b = blockIdx.x;
    int t = threadIdx.x;
    int beg = crow[b], end = crow[b + 1];
    int m = end - beg;
    bool inLds = (m <= BCAP);
    if (inLds) for (int j = t; j < m; j += 256) ebuf[j] = part[beg + j];
    int node0 = b << 8;
    int nnode = NN - node0 < 256 ? NN - node0 : 256;
    cnt[t] = 0;
    __syncthreads();
    for (int j = t; j < m; j += 256)
        atomicAdd(&cnt[(inLds ? ebuf[j] : part[beg + j]) >> 17], 1);
    __syncthreads();
    int v = cnt[t];
    sc[t] = v;
    __syncthreads();
    for (int off = 1; off < 256; off <<= 1) {
        int add = (t >= off) ? sc[t - off] : 0;
        __syncthreads();
        sc[t] += add;
        __syncthreads();
    }
    int excl = sc[t] - v;
    if (t < nnode) {
        rowptr[node0 + t] = beg + excl;
        dinv[node0 + t] = rsqrtf((float)v + 1.0f);
    }
    if (b == NBUCK - 1 && t == 0) rowptr[NN] = E;
    __syncthreads();
    cnt[t] = beg + excl;    // reuse as cursor
    __syncthreads();
    for (int j = t; j < m; j += 256) {
        int e = inLds ? ebuf[j] : part[beg + j];
        int pos = atomicAdd(&cnt[e >> 17], 1);
        ssrc[pos] = e & 0x1FFFF;
    }
}

// ---------------- MFMA GEMM: U[n][64] = bf16((X @ W) * dinv[row]) ------------
// (R14, kept.) 64x64 tile/block, 4 waves; wave w owns rows w*16..+15.
// C/D: col=lane&15, row=(lane>>4)*4+reg [m89-verified]. Stride K+8 u16 -> 2-way free.
template <int K, typename XT>
__global__ __launch_bounds__(256, 4) void k_gemm(const XT* __restrict__ X,
                                                 const float* __restrict__ W,
                                                 const float* __restrict__ dinv,
                                                 u16* __restrict__ U, int n) {
    constexpr int XS = K + 8;
    __shared__ __align__(16) u16 xb[64 * XS];
    __shared__ __align__(16) u16 wt[64 * XS];
    int tid = threadIdx.x;
    int lane = tid & 63, wid = tid >> 6;
    int row0 = blockIdx.x * 64;
    for (int idx = tid; idx < 64 * (K / 4); idx += 256) {
        int r = idx / (K / 4), c4 = idx % (K / 4);
        int row = row0 + r;
        ushort4 o = {0, 0, 0, 0};
        if (row < n) {
            if constexpr (sizeof(XT) == 4) {
                float4 v = *reinterpret_cast<const float4*>(&X[(size_t)row * K + c4 * 4]);
                o.x = f2bf(v.x); o.y = f2bf(v.y); o.z = f2bf(v.z); o.w = f2bf(v.w);
            } else {
                o = *reinterpret_cast<const ushort4*>(&X[(size_t)row * K + c4 * 4]);
            }
        }
        *reinterpret_cast<ushort4*>(&xb[r * XS + c4 * 4]) = o;
    }
    for (int idx = tid; idx < K * 64; idx += 256) {
        int k = idx >> 6, c = idx & 63;
        wt[c * XS + k] = f2bf(W[(size_t)k * 64 + c]);
    }
    __syncthreads();
    int lr = lane & 15, kb = lane >> 4;
    f32x4 acc0 = {0.f, 0.f, 0.f, 0.f};
    f32x4 acc1 = {0.f, 0.f, 0.f, 0.f};
    f32x4 acc2 = {0.f, 0.f, 0.f, 0.f};
    f32x4 acc3 = {0.f, 0.f, 0.f, 0.f};
#pragma unroll
    for (int kc = 0; kc < K; kc += 32) {
        bf16x8 a  = *reinterpret_cast<const bf16x8*>(&xb[(wid * 16 + lr) * XS + kc + kb * 8]);
        bf16x8 b0 = *reinterpret_cast<const bf16x8*>(&wt[( 0 + lr) * XS + kc + kb * 8]);
        bf16x8 b1 = *reinterpret_cast<const bf16x8*>(&wt[(16 + lr) * XS + kc + kb * 8]);
        bf16x8 b2 = *reinterpret_cast<const bf16x8*>(&wt[(32 + lr) * XS + kc + kb * 8]);
        bf16x8 b3 = *reinterpret_cast<const bf16x8*>(&wt[(48 + lr) * XS + kc + kb * 8]);
        acc0 = __builtin_amdgcn_mfma_f32_16x16x32_bf16(a, b0, acc0, 0, 0, 0);
        acc1 = __builtin_amdgcn_mfma_f32_16x16x32_bf16(a, b1, acc1, 0, 0, 0);
        acc2 = __builtin_amdgcn_mfma_f32_16x16x32_bf16(a, b2, acc2, 0, 0, 0);
        acc3 = __builtin_amdgcn_mfma_f32_16x16x32_bf16(a, b3, acc3, 0, 0, 0);
    }
#pragma unroll
    for (int reg = 0; reg < 4; ++reg) {
        int row = row0 + wid * 16 + kb * 4 + reg;
        if (row < n) {
            float dv = dinv[row];
            U[(size_t)row * 64 +  0 + lr] = f2bf(acc0[reg] * dv);
            U[(size_t)row * 64 + 16 + lr] = f2bf(acc1[reg] * dv);
            U[(size_t)row * 64 + 32 + lr] = f2bf(acc2[reg] * dv);
            U[(size_t)row * 64 + 48 + lr] = f2bf(acc3[reg] * dv);
        }
    }
}

// packed accumulate: per u32 -> 2 unpack VALU + 1 v_pk_add_f32 (vs 2+2 scalar)
#define ACCV(u, A0, A1, A2, A3) \
    A0 += unpk(u.x); A1 += unpk(u.y); A2 += unpk(u.z); A3 += unpk(u.w);

// ---------------- gather-reduce per dst node (bf16 U rows, bf16 h out) --------
// h[d] = relu(dinv[d] * (sum_{s in N(d)} U[s] + U[d]) + b)
// R13 structure (2-deep ILP, grid-stride — R12/R14/R16 lesson: DO NOT chunk or
// deepen). R18: f32x2 packed accumulators (v_pk_add_f32, -25% VALU) +
// non-temporal ssrc loads (keep streamed index array out of L2; U stays hot).
__global__ void k_gather(const int* __restrict__ rowptr, const int* __restrict__ ssrc,
                         const float* __restrict__ dinv, const u16* __restrict__ U,
                         const float* __restrict__ bias,
                         u16* __restrict__ outbuf, int n) {
    int gtid = blockIdx.x * blockDim.x + threadIdx.x;
    int lane = gtid & 63;
    int g = lane & 7;        // edge slot
    int c = lane >> 3;       // 16B chunk within the 128B row (0..7)
    int w = gtid >> 6;
    int nw = (gridDim.x * blockDim.x) >> 6;
    float bv = bias[lane];
    for (int d = w; d < n; d += nw) {
        int beg = rowptr[d], end = rowptr[d + 1];
        f32x2 a0_0 = {0.f,0.f}, a0_1 = {0.f,0.f}, a0_2 = {0.f,0.f}, a0_3 = {0.f,0.f};
        f32x2 a1_0 = {0.f,0.f}, a1_1 = {0.f,0.f}, a1_2 = {0.f,0.f}, a1_3 = {0.f,0.f};
        int j = beg;
        for (; j + 16 <= end; j += 16) {
            int s0 = __builtin_nontemporal_load(&ssrc[j + g]);
            int s1 = __builtin_nontemporal_load(&ssrc[j + 8 + g]);
            uint4 u0 = *reinterpret_cast<const uint4*>(&U[(size_t)s0 * 64 + c * 8]);
            uint4 u1 = *reinterpret_cast<const uint4*>(&U[(size_t)s1 * 64 + c * 8]);
            ACCV(u0, a0_0, a0_1, a0_2, a0_3);
            ACCV(u1, a1_0, a1_1, a1_2, a1_3);
        }
        if (j + 8 <= end) {
            int s0 = __builtin_nontemporal_load(&ssrc[j + g]);
            uint4 u0 = *reinterpret_cast<const uint4*>(&U[(size_t)s0 * 64 + c * 8]);
            ACCV(u0, a0_0, a0_1, a0_2, a0_3);
            j += 8;
        }
        if (j + g < end) {
            int s1 = __builtin_nontemporal_load(&ssrc[j + g]);
            uint4 u1 = *reinterpret_cast<const uint4*>(&U[(size_t)s1 * 64 + c * 8]);
            ACCV(u1, a1_0, a1_1, a1_2, a1_3);
        }
        a0_0 += a1_0; a0_1 += a1_1; a0_2 += a1_2; a0_3 += a1_3;
        // reduce over the 8 edge slots (xor 1,2,4), per component
#pragma unroll
        for (int m = 1; m <= 4; m <<= 1) {
            a0_0.x += __shfl_xor(a0_0.x, m); a0_0.y += __shfl_xor(a0_0.y, m);
            a0_1.x += __shfl_xor(a0_1.x, m); a0_1.y += __shfl_xor(a0_1.y, m);
            a0_2.x += __shfl_xor(a0_2.x, m); a0_2.y += __shfl_xor(a0_2.y, m);
            a0_3.x += __shfl_xor(a0_3.x, m); a0_3.y += __shfl_xor(a0_3.y, m);
        }
        // channel = c*8 + g = lane; chan pairs: a_k = {ch 2k, ch 2k+1}
        f32x2 q = (g & 4) ? ((g & 2) ? a0_3 : a0_2) : ((g & 2) ? a0_1 : a0_0);
        float hv = (g & 1) ? q.y : q.x;
        float ud = __uint_as_float(((u32)U[(size_t)d * 64 + lane]) << 16);
        float dd = dinv[d];
        float h = (hv + ud) * dd + bv;
        h = h > 0.f ? h : 0.f;
        outbuf[(size_t)d * 64 + lane] = f2bf(h);   // coalesced 128B wave store
    }
}

// ---------------- pool: segmented sum over sorted batch (bf16 h) --------------
__global__ __launch_bounds__(256) void k_pool(const u16* __restrict__ h,
                                              const int* __restrict__ batch,
                                              float* __restrict__ sums, int n) {
    int tid = blockIdx.x * blockDim.x + threadIdx.x;
    int wave = tid >> 6;
    int lane = tid & 63;
    int node0 = wave * 64;
    if (node0 >= n) return;
    int nodeEnd = min(n, node0 + 64);
    float acc = 0.f;
    int curg = batch[node0];
    for (int nd = node0; nd < nodeEnd; ++nd) {
        int g = batch[nd];
        if (g != curg) {
            atomicAdd(&sums[(size_t)curg * 64 + lane], acc);
            acc = 0.f;
            curg = g;
        }
        acc += __uint_as_float(((u32)h[(size_t)nd * 64 + lane]) << 16);
    }
    atomicAdd(&sums[(size_t)curg * 64 + lane], acc);
}

// ---------------- head: out[g] = (sums[g]/cnt[g]) @ Wl + bl ------------------
// cnt[g] from binary search over sorted batch (no contended atomics).
__global__ void k_final(const float* __restrict__ sums, const int* __restrict__ batch,
                        const float* __restrict__ Wl, const float* __restrict__ bl,
                        float* __restrict__ out, int n) {
    __shared__ float pooled[64];
    int g = blockIdx.x;
    int t = threadIdx.x;
    int lo = 0, hi = n;
    while (lo < hi) { int m = (lo + hi) >> 1; if (batch[m] < g) lo = m + 1; else hi = m; }
    int lo2 = lo, hi2 = n;
    while (lo2 < hi2) { int m = (lo2 + hi2) >> 1; if (batch[m] < g + 1) lo2 = m + 1; else hi2 = m; }
    float c = (float)(lo2 - lo);
    c = c < 1.0f ? 1.0f : c;
    pooled[t] = sums[g * 64 + t] / c;
    __syncthreads();
    if (t < 32) {
        float acc = bl[t];
#pragma unroll 8
        for (int k = 0; k < 64; k++) acc += pooled[k] * Wl[k * 32 + t];
        out[g * 32 + t] = acc;
    }
}

extern "C" void kernel_launch(void* const* d_in, const int* in_sizes, int n_in,
                              void* d_out, int out_size, void* d_ws, size_t ws_size,
                              hipStream_t stream) {
    const float* x = (const float*)d_in[0];
    const int* ei = (const int*)d_in[1];      // [2, E] int32
    const int* batch = (const int*)d_in[2];   // [N] int32
    const float* W1 = (const float*)d_in[4];
    const float* b1 = (const float*)d_in[5];
    const float* W2 = (const float*)d_in[6];
    const float* b2 = (const float*)d_in[7];
    const float* Wl = (const float*)d_in[8];
    const float* bl = (const float*)d_in[9];
    float* out = (float*)d_out;

    const int* esrc = ei;
    const int* edst = ei + NE;

    char* ws = (char*)d_ws;
    size_t off = 0;
    auto alloc = [&](size_t bytes) {
        void* p = ws + off;
        off += (bytes + 255) & ~size_t(255);
        return p;
    };
    float* dinv   = (float*)alloc((size_t)NN * 4);
    int*   rowptr = (int*)alloc((size_t)(NN + 1) * 4);
    int*   HM     = (int*)alloc((size_t)NM * 4);        // 0.8 MB scan matrix
    int*   bsum   = (int*)alloc((size_t)(NMB + 1) * 4);
    int*   crow   = (int*)alloc((size_t)(NBUCK + 1) * 4);
    int*   ssrc   = (int*)alloc((size_t)NE * 4);        // 12.8 MB
    u16*   tbuf   = (u16*)alloc((size_t)NE * 4);        // 12.8 MB: part overlay / U1/U2
    u16*   agg    = (u16*)alloc((size_t)NN * HD * 2);   // 12.8 MB (h1/h2 bf16)
    float* sums   = (float*)alloc((size_t)NG * HD * 4);
    // part overlays tbuf: dead before gemm1 writes tbuf
    int* part = (int*)tbuf;

    // 1. contention-free radix partition -> ssrc (+ rowptr, dinv, crow)
    k_blkhist<<<NPB, 256, 0, stream>>>(edst, HM, NE);
    k_scanA<<<NMB, 1024, 0, stream>>>(HM, bsum, NM);
    k_place<<<NPB, 256, 0, stream>>>(esrc, edst, HM, bsum, part, crow, NE);
    k_phaseB<<<NBUCK, 256, 0, stream>>>(part, crow, rowptr, ssrc, dinv, NE);

    // 2. layer 1: U1 = bf16((x@W1)*dinv) ; h1 = bf16(relu(...)) -> agg
    k_gemm<DIN, float><<<(NN + 63) / 64, 256, 0, stream>>>(x, W1, dinv, tbuf, NN);
    k_gather<<<2048, 256, 0, stream>>>(rowptr, ssrc, dinv, tbuf, b1, agg, NN);

    // 3. layer 2: U2 = bf16((h1@W2)*dinv) ; h2 -> agg (h1 dead after gemm2)
    k_gemm<HD, u16><<<(NN + 63) / 64, 256, 0, stream>>>(agg, W2, dinv, tbuf, NN);
    k_gather<<<2048, 256, 0, stream>>>(rowptr, ssrc, dinv, tbuf, b2, agg, NN);

    // 4. pool (segmented, conflict-free flushes) + head (binary-search counts)
    hipMemsetAsync(sums, 0, (size_t)NG * HD * 4, stream);
    k_pool<<<(NN + 255) / 256, 256, 0, stream>>>(agg, batch, sums, NN);
    k_final<<<NG, 64, 0, stream>>>(sums, batch, Wl, bl, out, NN);
}

// Round 19
// 255.049 us; speedup vs baseline: 1.0454x; 1.0454x over previous
//
#include <hip/hip_runtime.h>

#define NN 100000
#define NE 3200000
#define DIN 128
#define HD 64
#define DEMB 32
#define NG 256
#define NBUCK ((NN + 255) / 256)        // 391 coarse buckets of 256 dst-nodes
#define NPB 512                         // partition blocks
#define CHUNK ((NE + NPB - 1) / NPB)    // 6250 edges per partition block
#define NM (NBUCK * NPB)                // 200192 histogram-matrix entries
#define NMB ((NM + 1023) / 1024)        // 196 scan blocks
#define BCAP 10240                      // phaseB LDS bucket cap (mean 8192, +22 sigma)

typedef unsigned short u16;
typedef unsigned int u32;
typedef __attribute__((ext_vector_type(8))) short bf16x8;
typedef __attribute__((ext_vector_type(4))) float f32x4;
typedef __attribute__((ext_vector_type(2))) float f32x2;

__device__ __forceinline__ float bflo(u32 u) { return __uint_as_float(u << 16); }
__device__ __forceinline__ float bfhi(u32 u) { return __uint_as_float(u & 0xffff0000u); }
__device__ __forceinline__ u16 f2bf(float f) {          // round-to-nearest-even
    u32 u = __float_as_uint(f);
    return (u16)((u + 0x7fffu + ((u >> 16) & 1u)) >> 16);
}
__device__ __forceinline__ f32x2 unpk(u32 u) {          // {lo, hi} bf16 -> f32 pair
    f32x2 r; r.x = bflo(u); r.y = bfhi(u); return r;
}

// ---------------- pass A: per-block coarse histogram (no global atomics) -----
__global__ __launch_bounds__(256) void k_blkhist(const int* __restrict__ dst,
                                                 int* __restrict__ HM, int E) {
    __shared__ int h[NBUCK];
    int blk = blockIdx.x, t = threadIdx.x;
    for (int i = t; i < NBUCK; i += 256) h[i] = 0;
    __syncthreads();
    int beg = blk * CHUNK, end = min(E, beg + CHUNK);
    for (int j = beg + t; j < end; j += 256) atomicAdd(&h[dst[j] >> 8], 1);
    __syncthreads();
    for (int i = t; i < NBUCK; i += 256) HM[i * NPB + blk] = h[i];  // bucket-major
}

// ---------------- scan pass 1: in-place per-1024-block exclusive scan --------
__global__ __launch_bounds__(1024) void k_scanA(int* __restrict__ HM,
                                                int* __restrict__ bsum, int n) {
    __shared__ int s[1024];
    int t = threadIdx.x;
    int idx = blockIdx.x * 1024 + t;
    int v = (idx < n) ? HM[idx] : 0;
    s[t] = v;
    __syncthreads();
    for (int off = 1; off < 1024; off <<= 1) {
        int add = (t >= off) ? s[t - off] : 0;
        __syncthreads();
        s[t] += add;
        __syncthreads();
    }
    if (idx < n) HM[idx] = s[t] - v;            // exclusive within block
    if (t == 1023) bsum[blockIdx.x] = s[t];     // block total
}

// ---------------- pass C: place edges; local bsum-scan replaces scan2/scanC --
// part[pos] = src | (dst&255)<<17 ; block 0 emits crow[] (absolute bucket starts)
__global__ __launch_bounds__(256) void k_place(const int* __restrict__ src,
                                               const int* __restrict__ dst,
                                               const int* __restrict__ HM,
                                               const int* __restrict__ bsum,
                                               int* __restrict__ part,
                                               int* __restrict__ crow, int E) {
    __shared__ int cur[NBUCK];
    __shared__ int sb[256];
    __shared__ int sbe[256];    // exclusive scan of bsum
    int blk = blockIdx.x, t = threadIdx.x;
    int v = (t < NMB) ? bsum[t] : 0;
    sb[t] = v;
    __syncthreads();
    for (int off = 1; off < 256; off <<= 1) {
        int add = (t >= off) ? sb[t - off] : 0;
        __syncthreads();
        sb[t] += add;
        __syncthreads();
    }
    sbe[t] = sb[t] - v;
    __syncthreads();
    for (int i = t; i < NBUCK; i += 256) {
        int idx = i * NPB + blk;
        int absv = HM[idx] + sbe[idx >> 10];
        cur[i] = absv;
        if (blk == 0) crow[i] = absv;   // blk 0 cursor = absolute bucket start
    }
    if (blk == 0 && t == 0) crow[NBUCK] = E;
    __syncthreads();
    int beg = blk * CHUNK, end = min(E, beg + CHUNK);
    for (int j = beg + t; j < end; j += 256) {
        int d = dst[j], s = src[j];
        int pos = atomicAdd(&cur[d >> 8], 1);   // LDS atomic — no global contention
        part[pos] = s | ((d & 255) << 17);
    }
}

// ---------------- phase B: per-bucket fine sort + degree + rowptr + dinv -----
// bucket staged in LDS (one global read instead of two); crow gives ranges.
__global__ __launch_bounds__(256) void k_phaseB(const int* __restrict__ part,
                                                const int* __restrict__ crow,
                                                int* __restrict__ rowptr,
                                                int* __restrict__ ssrc,
                                                float* __restrict__ dinv, int E) {
    __shared__ int cnt[256];
    __shared__ int sc[256];
    __shared__ int ebuf[BCAP];
    int b = blockIdx.x;
    int t = threadIdx.x;
    int beg = crow[b], end = crow[b + 1];
    int m = end - beg;
    bool inLds = (m <= BCAP);
    if (inLds) for (int j = t; j < m; j += 256) ebuf[j] = part[beg + j];
    int node0 = b << 8;
    int nnode = NN - node0 < 256 ? NN - node0 : 256;
    cnt[t] = 0;
    __syncthreads();
    for (int j = t; j < m; j += 256)
        atomicAdd(&cnt[(inLds ? ebuf[j] : part[beg + j]) >> 17], 1);
    __syncthreads();
    int v = cnt[t];
    sc[t] = v;
    __syncthreads();
    for (int off = 1; off < 256; off <<= 1) {
        int add = (t >= off) ? sc[t - off] : 0;
        __syncthreads();
        sc[t] += add;
        __syncthreads();
    }
    int excl = sc[t] - v;
    if (t < nnode) {
        rowptr[node0 + t] = beg + excl;
        dinv[node0 + t] = rsqrtf((float)v + 1.0f);
    }
    if (b == NBUCK - 1 && t == 0) rowptr[NN] = E;
    __syncthreads();
    cnt[t] = beg + excl;    // reuse as cursor
    __syncthreads();
    for (int j = t; j < m; j += 256) {
        int e = inLds ? ebuf[j] : part[beg + j];
        int pos = atomicAdd(&cnt[e >> 17], 1);
        ssrc[pos] = e & 0x1FFFF;
    }
}

// ---------------- MFMA GEMM: U[n][64] = bf16((X @ W) * dinv[row]) ------------
// (R14, kept.) 64x64 tile/block, 4 waves; wave w owns rows w*16..+15.
// C/D: col=lane&15, row=(lane>>4)*4+reg [m89-verified]. Stride K+8 u16 -> 2-way free.
template <int K, typename XT>
__global__ __launch_bounds__(256, 4) void k_gemm(const XT* __restrict__ X,
                                                 const float* __restrict__ W,
                                                 const float* __restrict__ dinv,
                                                 u16* __restrict__ U, int n) {
    constexpr int XS = K + 8;
    __shared__ __align__(16) u16 xb[64 * XS];
    __shared__ __align__(16) u16 wt[64 * XS];
    int tid = threadIdx.x;
    int lane = tid & 63, wid = tid >> 6;
    int row0 = blockIdx.x * 64;
    for (int idx = tid; idx < 64 * (K / 4); idx += 256) {
        int r = idx / (K / 4), c4 = idx % (K / 4);
        int row = row0 + r;
        ushort4 o = {0, 0, 0, 0};
        if (row < n) {
            if constexpr (sizeof(XT) == 4) {
                float4 v = *reinterpret_cast<const float4*>(&X[(size_t)row * K + c4 * 4]);
                o.x = f2bf(v.x); o.y = f2bf(v.y); o.z = f2bf(v.z); o.w = f2bf(v.w);
            } else {
                o = *reinterpret_cast<const ushort4*>(&X[(size_t)row * K + c4 * 4]);
            }
        }
        *reinterpret_cast<ushort4*>(&xb[r * XS + c4 * 4]) = o;
    }
    for (int idx = tid; idx < K * 64; idx += 256) {
        int k = idx >> 6, c = idx & 63;
        wt[c * XS + k] = f2bf(W[(size_t)k * 64 + c]);
    }
    __syncthreads();
    int lr = lane & 15, kb = lane >> 4;
    f32x4 acc0 = {0.f, 0.f, 0.f, 0.f};
    f32x4 acc1 = {0.f, 0.f, 0.f, 0.f};
    f32x4 acc2 = {0.f, 0.f, 0.f, 0.f};
    f32x4 acc3 = {0.f, 0.f, 0.f, 0.f};
#pragma unroll
    for (int kc = 0; kc < K; kc += 32) {
        bf16x8 a  = *reinterpret_cast<const bf16x8*>(&xb[(wid * 16 + lr) * XS + kc + kb * 8]);
        bf16x8 b0 = *reinterpret_cast<const bf16x8*>(&wt[( 0 + lr) * XS + kc + kb * 8]);
        bf16x8 b1 = *reinterpret_cast<const bf16x8*>(&wt[(16 + lr) * XS + kc + kb * 8]);
        bf16x8 b2 = *reinterpret_cast<const bf16x8*>(&wt[(32 + lr) * XS + kc + kb * 8]);
        bf16x8 b3 = *reinterpret_cast<const bf16x8*>(&wt[(48 + lr) * XS + kc + kb * 8]);
        acc0 = __builtin_amdgcn_mfma_f32_16x16x32_bf16(a, b0, acc0, 0, 0, 0);
        acc1 = __builtin_amdgcn_mfma_f32_16x16x32_bf16(a, b1, acc1, 0, 0, 0);
        acc2 = __builtin_amdgcn_mfma_f32_16x16x32_bf16(a, b2, acc2, 0, 0, 0);
        acc3 = __builtin_amdgcn_mfma_f32_16x16x32_bf16(a, b3, acc3, 0, 0, 0);
    }
#pragma unroll
    for (int reg = 0; reg < 4; ++reg) {
        int row = row0 + wid * 16 + kb * 4 + reg;
        if (row < n) {
            float dv = dinv[row];
            U[(size_t)row * 64 +  0 + lr] = f2bf(acc0[reg] * dv);
            U[(size_t)row * 64 + 16 + lr] = f2bf(acc1[reg] * dv);
            U[(size_t)row * 64 + 32 + lr] = f2bf(acc2[reg] * dv);
            U[(size_t)row * 64 + 48 + lr] = f2bf(acc3[reg] * dv);
        }
    }
}

// packed accumulate: per u32 -> 2 unpack VALU + 1 v_pk_add_f32
#define ACCV(u, A0, A1, A2, A3) \
    A0 += unpk(u.x); A1 += unpk(u.y); A2 += unpk(u.z); A3 += unpk(u.w);

// ---------------- gather-reduce per dst node (bf16 U rows, bf16 h out) --------
// h[d] = relu(dinv[d] * (sum_{s in N(d)} U[s] + U[d]) + b)
// R13 structure (2-deep ILP, grid-stride, VGPR ~24 — R12/R14/R16: DO NOT chunk
// or deepen). R18 lessons: NT ssrc loads LOSE (cross-wave L2 reuse, +9MB FETCH)
// — reverted; packed f32x2 adds kept (harmless). R19: index software-pipeline —
// prefetch next iter's s0/s1 before accumulating, breaking the serial
// ssrc->addr->U chain per iteration.
__global__ void k_gather(const int* __restrict__ rowptr, const int* __restrict__ ssrc,
                         const float* __restrict__ dinv, const u16* __restrict__ U,
                         const float* __restrict__ bias,
                         u16* __restrict__ outbuf, int n) {
    int gtid = blockIdx.x * blockDim.x + threadIdx.x;
    int lane = gtid & 63;
    int g = lane & 7;        // edge slot
    int c = lane >> 3;       // 16B chunk within the 128B row (0..7)
    int w = gtid >> 6;
    int nw = (gridDim.x * blockDim.x) >> 6;
    float bv = bias[lane];
    for (int d = w; d < n; d += nw) {
        int beg = rowptr[d], end = rowptr[d + 1];
        f32x2 a0_0 = {0.f,0.f}, a0_1 = {0.f,0.f}, a0_2 = {0.f,0.f}, a0_3 = {0.f,0.f};
        f32x2 a1_0 = {0.f,0.f}, a1_1 = {0.f,0.f}, a1_2 = {0.f,0.f}, a1_3 = {0.f,0.f};
        int j = beg;
        int s0 = 0, s1 = 0;
        if (j + 16 <= end) { s0 = ssrc[j + g]; s1 = ssrc[j + 8 + g]; }
        while (j + 16 <= end) {
            uint4 u0 = *reinterpret_cast<const uint4*>(&U[(size_t)s0 * 64 + c * 8]);
            uint4 u1 = *reinterpret_cast<const uint4*>(&U[(size_t)s1 * 64 + c * 8]);
            j += 16;
            if (j + 16 <= end) {            // prefetch next indices while U loads fly
                s0 = ssrc[j + g];
                s1 = ssrc[j + 8 + g];
            }
            ACCV(u0, a0_0, a0_1, a0_2, a0_3);
            ACCV(u1, a1_0, a1_1, a1_2, a1_3);
        }
        if (j + 8 <= end) {
            int t0 = ssrc[j + g];
            uint4 u0 = *reinterpret_cast<const uint4*>(&U[(size_t)t0 * 64 + c * 8]);
            ACCV(u0, a0_0, a0_1, a0_2, a0_3);
            j += 8;
        }
        if (j + g < end) {
            int t1 = ssrc[j + g];
            uint4 u1 = *reinterpret_cast<const uint4*>(&U[(size_t)t1 * 64 + c * 8]);
            ACCV(u1, a1_0, a1_1, a1_2, a1_3);
        }
        a0_0 += a1_0; a0_1 += a1_1; a0_2 += a1_2; a0_3 += a1_3;
        // reduce over the 8 edge slots (xor 1,2,4), per component
#pragma unroll
        for (int m = 1; m <= 4; m <<= 1) {
            a0_0.x += __shfl_xor(a0_0.x, m); a0_0.y += __shfl_xor(a0_0.y, m);
            a0_1.x += __shfl_xor(a0_1.x, m); a0_1.y += __shfl_xor(a0_1.y, m);
            a0_2.x += __shfl_xor(a0_2.x, m); a0_2.y += __shfl_xor(a0_2.y, m);
            a0_3.x += __shfl_xor(a0_3.x, m); a0_3.y += __shfl_xor(a0_3.y, m);
        }
        // channel = c*8 + g = lane; chan pairs: a_k = {ch 2k, ch 2k+1}
        f32x2 q = (g & 4) ? ((g & 2) ? a0_3 : a0_2) : ((g & 2) ? a0_1 : a0_0);
        float hv = (g & 1) ? q.y : q.x;
        float ud = __uint_as_float(((u32)U[(size_t)d * 64 + lane]) << 16);
        float dd = dinv[d];
        float h = (hv + ud) * dd + bv;
        h = h > 0.f ? h : 0.f;
        outbuf[(size_t)d * 64 + lane] = f2bf(h);   // coalesced 128B wave store
    }
}

// ---------------- pool: segmented sum over sorted batch (bf16 h) --------------
__global__ __launch_bounds__(256) void k_pool(const u16* __restrict__ h,
                                              const int* __restrict__ batch,
                                              float* __restrict__ sums, int n) {
    int tid = blockIdx.x * blockDim.x + threadIdx.x;
    int wave = tid >> 6;
    int lane = tid & 63;
    int node0 = wave * 64;
    if (node0 >= n) return;
    int nodeEnd = min(n, node0 + 64);
    float acc = 0.f;
    int curg = batch[node0];
    for (int nd = node0; nd < nodeEnd; ++nd) {
        int g = batch[nd];
        if (g != curg) {
            atomicAdd(&sums[(size_t)curg * 64 + lane], acc);
            acc = 0.f;
            curg = g;
        }
        acc += __uint_as_float(((u32)h[(size_t)nd * 64 + lane]) << 16);
    }
    atomicAdd(&sums[(size_t)curg * 64 + lane], acc);
}

// ---------------- head: out[g] = (sums[g]/cnt[g]) @ Wl + bl ------------------
// cnt[g] from binary search over sorted batch (no contended atomics).
__global__ void k_final(const float* __restrict__ sums, const int* __restrict__ batch,
                        const float* __restrict__ Wl, const float* __restrict__ bl,
                        float* __restrict__ out, int n) {
    __shared__ float pooled[64];
    int g = blockIdx.x;
    int t = threadIdx.x;
    int lo = 0, hi = n;
    while (lo < hi) { int m = (lo + hi) >> 1; if (batch[m] < g) lo = m + 1; else hi = m; }
    int lo2 = lo, hi2 = n;
    while (lo2 < hi2) { int m = (lo2 + hi2) >> 1; if (batch[m] < g + 1) lo2 = m + 1; else hi2 = m; }
    float c = (float)(lo2 - lo);
    c = c < 1.0f ? 1.0f : c;
    pooled[t] = sums[g * 64 + t] / c;
    __syncthreads();
    if (t < 32) {
        float acc = bl[t];
#pragma unroll 8
        for (int k = 0; k < 64; k++) acc += pooled[k] * Wl[k * 32 + t];
        out[g * 32 + t] = acc;
    }
}

extern "C" void kernel_launch(void* const* d_in, const int* in_sizes, int n_in,
                              void* d_out, int out_size, void* d_ws, size_t ws_size,
                              hipStream_t stream) {
    const float* x = (const float*)d_in[0];
    const int* ei = (const int*)d_in[1];      // [2, E] int32
    const int* batch = (const int*)d_in[2];   // [N] int32
    const float* W1 = (const float*)d_in[4];
    const float* b1 = (const float*)d_in[5];
    const float* W2 = (const float*)d_in[6];
    const float* b2 = (const float*)d_in[7];
    const float* Wl = (const float*)d_in[8];
    const float* bl = (const float*)d_in[9];
    float* out = (float*)d_out;

    const int* esrc = ei;
    const int* edst = ei + NE;

    char* ws = (char*)d_ws;
    size_t off = 0;
    auto alloc = [&](size_t bytes) {
        void* p = ws + off;
        off += (bytes + 255) & ~size_t(255);
        return p;
    };
    float* dinv   = (float*)alloc((size_t)NN * 4);
    int*   rowptr = (int*)alloc((size_t)(NN + 1) * 4);
    int*   HM     = (int*)alloc((size_t)NM * 4);        // 0.8 MB scan matrix
    int*   bsum   = (int*)alloc((size_t)(NMB + 1) * 4);
    int*   crow   = (int*)alloc((size_t)(NBUCK + 1) * 4);
    int*   ssrc   = (int*)alloc((size_t)NE * 4);        // 12.8 MB
    u16*   tbuf   = (u16*)alloc((size_t)NE * 4);        // 12.8 MB: part overlay / U1/U2
    u16*   agg    = (u16*)alloc((size_t)NN * HD * 2);   // 12.8 MB (h1/h2 bf16)
    float* sums   = (float*)alloc((size_t)NG * HD * 4);
    // part overlays tbuf: dead before gemm1 writes tbuf
    int* part = (int*)tbuf;

    // 1. contention-free radix partition -> ssrc (+ rowptr, dinv, crow)
    k_blkhist<<<NPB, 256, 0, stream>>>(edst, HM, NE);
    k_scanA<<<NMB, 1024, 0, stream>>>(HM, bsum, NM);
    k_place<<<NPB, 256, 0, stream>>>(esrc, edst, HM, bsum, part, crow, NE);
    k_phaseB<<<NBUCK, 256, 0, stream>>>(part, crow, rowptr, ssrc, dinv, NE);

    // 2. layer 1: U1 = bf16((x@W1)*dinv) ; h1 = bf16(relu(...)) -> agg
    k_gemm<DIN, float><<<(NN + 63) / 64, 256, 0, stream>>>(x, W1, dinv, tbuf, NN);
    k_gather<<<2048, 256, 0, stream>>>(rowptr, ssrc, dinv, tbuf, b1, agg, NN);

    // 3. layer 2: U2 = bf16((h1@W2)*dinv) ; h2 -> agg (h1 dead after gemm2)
    k_gemm<HD, u16><<<(NN + 63) / 64, 256, 0, stream>>>(agg, W2, dinv, tbuf, NN);
    k_gather<<<2048, 256, 0, stream>>>(rowptr, ssrc, dinv, tbuf, b2, agg, NN);

    // 4. pool (segmented, conflict-free flushes) + head (binary-search counts)
    hipMemsetAsync(sums, 0, (size_t)NG * HD * 4, stream);
    k_pool<<<(NN + 255) / 256, 256, 0, stream>>>(agg, batch, sums, NN);
    k_final<<<NG, 64, 0, stream>>>(sums, batch, Wl, bl, out, NN);
}